// Round 15
// baseline (190.063 us; speedup 1.0000x reference)
//
#include <hip/hip_runtime.h>

#define D 64
#define LOG2E 1.4426950408889634f

#define HEPT_R 8                  // hist serial rounds (1024 thr -> 8192/block)
#define SEPT 8                    // edges/thread, scatter (1024 thr -> 8192/block)
#define BSH 7                     // bucket shift: 128-node buckets
#define BSZ 128                   // nodes per bucket

using frag_ab = __attribute__((ext_vector_type(8))) short;  // 8 bf16 (4 VGPRs)
using f32x4   = __attribute__((ext_vector_type(4))) float;  // 4 fp32 acc

__device__ __forceinline__ unsigned short f2bf(float f) {      // RNE fp32->bf16
    unsigned int bits = __float_as_uint(f);
    return (unsigned short)((bits + 0x7fffu + ((bits >> 16) & 1u)) >> 16);
}

__device__ __forceinline__ frag_ab pack8(float4 a, float4 b) { // 8 fp32 -> bf16x8 frag
    frag_ab f;
    f[0] = (short)f2bf(a.x); f[1] = (short)f2bf(a.y);
    f[2] = (short)f2bf(a.z); f[3] = (short)f2bf(a.w);
    f[4] = (short)f2bf(b.x); f[5] = (short)f2bf(b.y);
    f[6] = (short)f2bf(b.z); f[7] = (short)f2bf(b.w);
    return f;
}

// Block-role fused kernel at 1024 threads (R14 lesson: wave-depth at fixed chunk
// is the lever for latency-bound edge streaming). Blocks [0, histBlk): histogram
// dst>>BSH over an 8192-edge chunk in 8 serial rounds / 16 waves (was 32 / 4).
// Blocks [histBlk, ..): z = x @ W^T + b via MFMA bf16, 16 waves x 16 rows = 256
// rows per block — per-wave code identical to the 256-thread version (wave-local,
// no cross-wave LDS). zxb[row*64+c] = { bf16(z_c) | bf16(x_c)<<16 }.
__global__ __launch_bounds__(1024) void gemm_z_hist(const float* __restrict__ x,
                                                    const float* __restrict__ W,
                                                    const float* __restrict__ b,
                                                    unsigned int* __restrict__ zxb,
                                                    int n,
                                                    const int* __restrict__ dst,
                                                    int* __restrict__ hist2d,
                                                    int e_cnt, int histBlk,
                                                    int nb, int nblk) {
    __shared__ int cnt[2048];       // hist branch only (8 KB; nb <= 2048)
    int tid = threadIdx.x;

    if ((int)blockIdx.x < histBlk) {
        for (int i = tid; i < nb; i += 1024) cnt[i] = 0;
        __syncthreads();
        int base = blockIdx.x * (1024 * HEPT_R);
        for (int j = 0; j < HEPT_R; ++j) {
            int e = base + j * 1024 + tid;
            if (e < e_cnt) atomicAdd(&cnt[dst[e] >> BSH], 1);   // LDS atomic
        }
        __syncthreads();
        for (int i = tid; i < nb; i += 1024)
            hist2d[(size_t)i * nblk + blockIdx.x] = cnt[i];     // bin-major store
        return;
    }

    int row0 = (blockIdx.x - histBlk) * 256;
    int l  = tid & 63;    // lane
    int w  = tid >> 6;    // wave 0..15 -> rows w*16..w*16+15
    int lr = l & 15;      // A-row / B-col / D-col within 16-tile
    int hi = l >> 4;      // 0..3
    int lk = hi * 8;      // k offset within K=32 chunk

    // A frags straight from global: wave reads 16 contiguous 256B rows (4 KB)
    int arow = row0 + w * 16 + lr;
    int crow = (arow < n) ? arow : (n - 1);       // clamp; stores are guarded
    const float* xp = x + (size_t)crow * 64;
    frag_ab afr[2];
#pragma unroll
    for (int ks = 0; ks < 2; ++ks) {
        const float* ap = xp + ks * 32 + lk;
        afr[ks] = pack8(*(const float4*)ap, *(const float4*)(ap + 4));
    }

    // B frags straight from W (16 KB, L1/L2-resident; B^T == W so k contiguous)
    frag_ab bfr[4][2];
#pragma unroll
    for (int colt = 0; colt < 4; ++colt) {
#pragma unroll
        for (int ks = 0; ks < 2; ++ks) {
            const float* wp = W + (colt * 16 + lr) * 64 + ks * 32 + lk;
            bfr[colt][ks] = pack8(*(const float4*)wp, *(const float4*)(wp + 4));
        }
    }

    f32x4 zero = {0.f, 0.f, 0.f, 0.f};
    f32x4 acc[4] = {zero, zero, zero, zero};
#pragma unroll
    for (int ks = 0; ks < 2; ++ks) {
#pragma unroll
        for (int colt = 0; colt < 4; ++colt) {
            acc[colt] = __builtin_amdgcn_mfma_f32_16x16x32_bf16(
                afr[ks], bfr[colt][ks], acc[colt], 0, 0, 0);
        }
    }

    // D mapping: col=lane&15, row=(lane>>4)*4+reg (m89-verified).
    // xv re-read from global is L1-hot (this block just streamed these rows).
#pragma unroll
    for (int colt = 0; colt < 4; ++colt) {
        int col = colt * 16 + lr;
        float bb = b[col];
#pragma unroll
        for (int r = 0; r < 4; ++r) {
            int row = row0 + w * 16 + hi * 4 + r;
            int rrow = (row < n) ? row : (n - 1);
            float z  = acc[colt][r] + bb;
            float xv = x[(size_t)rrow * 64 + col];
            unsigned int u = (unsigned int)f2bf(z) |
                             ((unsigned int)f2bf(xv) << 16);
            if (row < n)
                zxb[(size_t)row * 64 + col] = u;   // 64B-segment coalesced
        }
    }
}

// ---- 3-phase coalesced scan over the bin-major histogram (atomic-free) ----
__global__ __launch_bounds__(256) void scan_part(const int* __restrict__ data,
                                                 int* __restrict__ part, int n) {
    __shared__ int red[256];
    int t = threadIdx.x;
    int i = blockIdx.x * 256 + t;
    red[t] = (i < n) ? data[i] : 0;
    __syncthreads();
    for (int off = 128; off >= 1; off >>= 1) {
        if (t < off) red[t] += red[t + off];
        __syncthreads();
    }
    if (t == 0) part[blockIdx.x] = red[0];
}

__global__ __launch_bounds__(1024) void scan_top(int* __restrict__ part, int B) {
    __shared__ int s[1024];
    int t = threadIdx.x;
    int v = (t < B) ? part[t] : 0;
    s[t] = v;
    __syncthreads();
    for (int off = 1; off < 1024; off <<= 1) {
        int u = (t >= off) ? s[t - off] : 0;
        __syncthreads();
        s[t] += u;
        __syncthreads();
    }
    if (t < B) part[t] = s[t] - v;   // exclusive
}

// in-place exclusive scan finalize (read-before-write, 1 thread per index).
// Writes total at data[n] as sentinel.
__global__ __launch_bounds__(256) void scan_final_ip(int* data,
                                                     const int* __restrict__ part, int n) {
    __shared__ int s[256];
    int t = threadIdx.x;
    int i = blockIdx.x * 256 + t;
    int v = (i < n) ? data[i] : 0;
    s[t] = v;
    __syncthreads();
    for (int off = 1; off < 256; off <<= 1) {
        int u = (t >= off) ? s[t - off] : 0;
        __syncthreads();
        s[t] += u;
        __syncthreads();
    }
    int incl = s[t] + part[blockIdx.x];
    if (i < n) data[i] = incl - v;
    if (i == n - 1) data[n] = incl;
}

// Partition edges into 128-node buckets: packed[pos] = src | (dst&127)<<24.
// Per-block bases come straight from the scanned 2D histogram -> disjoint output
// ranges with ZERO global atomics. SAME 8192-edge chunk (147 blocks, 10.5-int
// runs preserved — R8 lesson) at 1024 threads: 16 waves/CU, depth 8 (R14 win).
__global__ __launch_bounds__(1024) void msd_scatter(const int* __restrict__ src,
                                                    const int* __restrict__ dst,
                                                    const int* __restrict__ histS,
                                                    unsigned int* __restrict__ packed,
                                                    int e_cnt, int nb, int nblk) {
    __shared__ int cnt[1024];
    int t = threadIdx.x;
    int blk = blockIdx.x;
    for (int i = t; i < nb; i += 1024) cnt[i] = histS[(size_t)i * nblk + blk];
    __syncthreads();
    int base = blk * (1024 * SEPT);
    for (int j = 0; j < SEPT; ++j) {
        int e = base + j * 1024 + t;
        if (e < e_cnt) {
            int d = dst[e];
            int pos = atomicAdd(&cnt[d >> BSH], 1);          // LDS atomic only
            packed[pos] = (unsigned int)src[e] | ((unsigned int)(d & (BSZ - 1)) << 24);
        }
    }
}

// One block per 128-node bucket (~1536 edges avg, 782 blocks). LDS count + scan ->
// rowstart written directly; srcids scattered within the bucket's contiguous region.
__global__ __launch_bounds__(256) void bucket_csr(const unsigned int* __restrict__ packed,
                                                  const int* __restrict__ histS,
                                                  int* __restrict__ rowstart,
                                                  int* __restrict__ srcids,
                                                  int n, int e_cnt, int nb, int nblk) {
    __shared__ int cnt[128];
    __shared__ int sc[128];
    __shared__ int cur[128];
    int t = threadIdx.x;
    int b = blockIdx.x;
    int lo = histS[(size_t)b * nblk];
    int hi = histS[(size_t)(b + 1) * nblk];   // b==nb-1 hits sentinel == e_cnt
    int m = hi - lo;

    if (t < 128) cnt[t] = 0;
    __syncthreads();
    for (int i = t; i < m; i += 256)
        atomicAdd(&cnt[packed[lo + i] >> 24], 1);
    __syncthreads();
    if (t < 128) sc[t] = cnt[t];
    __syncthreads();
    for (int off = 1; off < 128; off <<= 1) {
        int u = (t < 128 && t >= off) ? sc[t - off] : 0;
        __syncthreads();
        if (t < 128) sc[t] += u;
        __syncthreads();
    }
    if (t < 128) {
        int excl = sc[t] - cnt[t];
        cur[t] = lo + excl;
        int node = (b << BSH) + t;
        if (node < n) rowstart[node] = lo + excl;
    }
    if (b == nb - 1 && t == 0) rowstart[n] = e_cnt;
    __syncthreads();
    for (int i = t; i < m; i += 256) {
        unsigned int p = packed[lo + i];
        int pos = atomicAdd(&cur[p >> 24], 1);     // LDS atomic
        srcids[pos] = (int)(p & 0xFFFFFFu);
    }
}

// wave-per-node, quarter-wave per edge, 8 edges/iter (2x unroll); unmasked full
// iterations + one masked tail. lrelu = max(v, 0.2v) (2 ops, slope < 1).
// bf16-packed row: zxb[row*64 + d] = { bf16 z_d | bf16 x_d << 16 }, 256 B/row.
__global__ __launch_bounds__(256) void gather4b(const int* __restrict__ srcids,
                                                const int* __restrict__ rowstart,
                                                const unsigned int* __restrict__ zxb,
                                                const float* __restrict__ att,
                                                float* __restrict__ out, int n) {
    int lane = threadIdx.x & 63;
    int node = blockIdx.x * 4 + (threadIdx.x >> 6);
    if (node >= n) return;
    int q = lane & 15;                 // dim group: 4q..4q+3
    int h = lane >> 4;                 // edge slot 0..3
    int rs = rowstart[node], re = rowstart[node + 1];

    const uint4 zdv = *(const uint4*)(zxb + (size_t)node * 64 + 4 * q);
    float zd0 = __uint_as_float(zdv.x << 16);
    float zd1 = __uint_as_float(zdv.y << 16);
    float zd2 = __uint_as_float(zdv.z << 16);
    float zd3 = __uint_as_float(zdv.w << 16);
    float4 av = *(const float4*)(att + 4 * q);
    float a0 = av.x * LOG2E, a1 = av.y * LOG2E, a2 = av.z * LOG2E, a3 = av.w * LOG2E;

    float ax0 = 0.f, ax1 = 0.f, ax2 = 0.f, ax3 = 0.f, ssum = 0.f;
    int efull = rs + ((re - rs) & ~7);
    int e = rs;
    for (; e < efull; e += 8) {            // unmasked body
        int s0 = srcids[e + h];
        int s1 = srcids[e + 4 + h];
        const uint4 r0 = *(const uint4*)(zxb + (size_t)s0 * 64 + 4 * q);
        const uint4 r1 = *(const uint4*)(zxb + (size_t)s1 * 64 + 4 * q);

        float v0 = __uint_as_float(r0.x << 16) + zd0; v0 = fmaxf(v0, 0.2f * v0);
        float v1 = __uint_as_float(r0.y << 16) + zd1; v1 = fmaxf(v1, 0.2f * v1);
        float v2 = __uint_as_float(r0.z << 16) + zd2; v2 = fmaxf(v2, 0.2f * v2);
        float v3 = __uint_as_float(r0.w << 16) + zd3; v3 = fmaxf(v3, 0.2f * v3);
        float p0 = v0 * a0 + v1 * a1 + v2 * a2 + v3 * a3;

        float u0 = __uint_as_float(r1.x << 16) + zd0; u0 = fmaxf(u0, 0.2f * u0);
        float u1 = __uint_as_float(r1.y << 16) + zd1; u1 = fmaxf(u1, 0.2f * u1);
        float u2 = __uint_as_float(r1.z << 16) + zd2; u2 = fmaxf(u2, 0.2f * u2);
        float u3 = __uint_as_float(r1.w << 16) + zd3; u3 = fmaxf(u3, 0.2f * u3);
        float p1 = u0 * a0 + u1 * a1 + u2 * a2 + u3 * a3;

#pragma unroll
        for (int off = 8; off >= 1; off >>= 1) {
            p0 += __shfl_xor(p0, off, 64);
            p1 += __shfl_xor(p1, off, 64);
        }
        float ex0 = __builtin_exp2f(p0);
        float ex1 = __builtin_exp2f(p1);
        ssum += ex0 + ex1;
        ax0 += ex0 * __uint_as_float(r0.x & 0xffff0000u)
             + ex1 * __uint_as_float(r1.x & 0xffff0000u);
        ax1 += ex0 * __uint_as_float(r0.y & 0xffff0000u)
             + ex1 * __uint_as_float(r1.y & 0xffff0000u);
        ax2 += ex0 * __uint_as_float(r0.z & 0xffff0000u)
             + ex1 * __uint_as_float(r1.z & 0xffff0000u);
        ax3 += ex0 * __uint_as_float(r0.w & 0xffff0000u)
             + ex1 * __uint_as_float(r1.w & 0xffff0000u);
    }
    if (e < re) {                          // masked tail (1..7 edges)
        int e0i = e + h, e1i = e + 4 + h;
        bool l0 = e0i < re, l1 = e1i < re;
        int s0 = l0 ? srcids[e0i] : node;
        int s1 = l1 ? srcids[e1i] : node;
        const uint4 r0 = *(const uint4*)(zxb + (size_t)s0 * 64 + 4 * q);
        const uint4 r1 = *(const uint4*)(zxb + (size_t)s1 * 64 + 4 * q);

        float v0 = __uint_as_float(r0.x << 16) + zd0; v0 = fmaxf(v0, 0.2f * v0);
        float v1 = __uint_as_float(r0.y << 16) + zd1; v1 = fmaxf(v1, 0.2f * v1);
        float v2 = __uint_as_float(r0.z << 16) + zd2; v2 = fmaxf(v2, 0.2f * v2);
        float v3 = __uint_as_float(r0.w << 16) + zd3; v3 = fmaxf(v3, 0.2f * v3);
        float p0 = v0 * a0 + v1 * a1 + v2 * a2 + v3 * a3;

        float u0 = __uint_as_float(r1.x << 16) + zd0; u0 = fmaxf(u0, 0.2f * u0);
        float u1 = __uint_as_float(r1.y << 16) + zd1; u1 = fmaxf(u1, 0.2f * u1);
        float u2 = __uint_as_float(r1.z << 16) + zd2; u2 = fmaxf(u2, 0.2f * u2);
        float u3 = __uint_as_float(r1.w << 16) + zd3; u3 = fmaxf(u3, 0.2f * u3);
        float p1 = u0 * a0 + u1 * a1 + u2 * a2 + u3 * a3;

#pragma unroll
        for (int off = 8; off >= 1; off >>= 1) {
            p0 += __shfl_xor(p0, off, 64);
            p1 += __shfl_xor(p1, off, 64);
        }
        float ex0 = l0 ? __builtin_exp2f(p0) : 0.f;
        float ex1 = l1 ? __builtin_exp2f(p1) : 0.f;
        ssum += ex0 + ex1;
        ax0 += ex0 * __uint_as_float(r0.x & 0xffff0000u)
             + ex1 * __uint_as_float(r1.x & 0xffff0000u);
        ax1 += ex0 * __uint_as_float(r0.y & 0xffff0000u)
             + ex1 * __uint_as_float(r1.y & 0xffff0000u);
        ax2 += ex0 * __uint_as_float(r0.z & 0xffff0000u)
             + ex1 * __uint_as_float(r1.z & 0xffff0000u);
        ax3 += ex0 * __uint_as_float(r0.w & 0xffff0000u)
             + ex1 * __uint_as_float(r1.w & 0xffff0000u);
    }
    ssum += __shfl_xor(ssum, 16, 64); ssum += __shfl_xor(ssum, 32, 64);
    ax0  += __shfl_xor(ax0, 16, 64);  ax0  += __shfl_xor(ax0, 32, 64);
    ax1  += __shfl_xor(ax1, 16, 64);  ax1  += __shfl_xor(ax1, 32, 64);
    ax2  += __shfl_xor(ax2, 16, 64);  ax2  += __shfl_xor(ax2, 32, 64);
    ax3  += __shfl_xor(ax3, 16, 64);  ax3  += __shfl_xor(ax3, 32, 64);
    if (h == 0) {
        float inv = (re > rs) ? 1.f / ssum : 0.f;
        float4 o = make_float4(ax0 * inv, ax1 * inv, ax2 * inv, ax3 * inv);
        *(float4*)&out[(size_t)node * D + 4 * q] = o;
    }
}

extern "C" void kernel_launch(void* const* d_in, const int* in_sizes, int n_in,
                              void* d_out, int out_size, void* d_ws, size_t ws_size,
                              hipStream_t stream) {
    const float* x   = (const float*)d_in[0];
    const int*   ei  = (const int*)d_in[1];
    const float* W   = (const float*)d_in[2];
    const float* b   = (const float*)d_in[3];
    const float* att = (const float*)d_in[4];
    int n = in_sizes[0] / D;
    int e = in_sizes[1] / 2;
    const int* src = ei;
    const int* dst = ei + e;
    float* out = (float*)d_out;

    int gemmBlk = (n + 255) / 256;                           // 391 (256 rows/block)
    int nb      = (n + BSZ - 1) >> BSH;                      // 782 buckets of 128
    int histBlk = (e + 1024 * HEPT_R - 1) / (1024 * HEPT_R); // 147 (same chunks)
    int nblk    = histBlk;
    int scatBlk = (e + 1024 * SEPT - 1) / (1024 * SEPT);     // 147 (same chunks)
    int NBH     = nb * nblk;                                 // 114954 cells
    int scanBlk = (NBH + 255) / 256;                         // 450 (<= 1024)

    // ws: zxb[n*64 uint] | hist2d[NBH+1] | rowstart[n+1] | srcids[e] | packed[e] | part[1024]
    unsigned int* zxb = (unsigned int*)d_ws;
    int* hist2d   = (int*)(zxb + (size_t)n * 64);
    int* rowstart = hist2d + NBH + 1;
    int* srcids   = rowstart + n + 1;
    unsigned int* packed = (unsigned int*)(srcids + e);
    int* part     = (int*)(packed + e);

    gemm_z_hist<<<histBlk + gemmBlk, 1024, 0, stream>>>(x, W, b, zxb, n,
                                                        dst, hist2d, e, histBlk, nb, nblk);
    scan_part<<<scanBlk, 256, 0, stream>>>(hist2d, part, NBH);
    scan_top<<<1, 1024, 0, stream>>>(part, scanBlk);
    scan_final_ip<<<scanBlk, 256, 0, stream>>>(hist2d, part, NBH);
    msd_scatter<<<scatBlk, 1024, 0, stream>>>(src, dst, hist2d, packed, e, nb, nblk);
    bucket_csr<<<nb, 256, 0, stream>>>(packed, hist2d, rowstart, srcids, n, e, nb, nblk);
    gather4b<<<(n + 3) / 4, 256, 0, stream>>>(srcids, rowstart, zxb, att, out, n);
}

// Round 16
// 186.951 us; speedup vs baseline: 1.0166x; 1.0166x over previous
//
#include <hip/hip_runtime.h>

#define D 64
#define LOG2E 1.4426950408889634f

#define HEPT_H 32                 // edges/thread, fused hist blocks (8192/block)
#define SEPT 8                    // edges/thread, scatter (1024 thr -> 8192/block)
#define BSH 7                     // bucket shift: 128-node buckets
#define BSZ 128                   // nodes per bucket

using frag_ab = __attribute__((ext_vector_type(8))) short;  // 8 bf16 (4 VGPRs)
using f32x4   = __attribute__((ext_vector_type(4))) float;  // 4 fp32 acc

__device__ __forceinline__ unsigned short f2bf(float f) {      // RNE fp32->bf16
    unsigned int bits = __float_as_uint(f);
    return (unsigned short)((bits + 0x7fffu + ((bits >> 16) & 1u)) >> 16);
}

__device__ __forceinline__ frag_ab pack8(float4 a, float4 b) { // 8 fp32 -> bf16x8 frag
    frag_ab f;
    f[0] = (short)f2bf(a.x); f[1] = (short)f2bf(a.y);
    f[2] = (short)f2bf(a.z); f[3] = (short)f2bf(a.w);
    f[4] = (short)f2bf(b.x); f[5] = (short)f2bf(b.y);
    f[6] = (short)f2bf(b.z); f[7] = (short)f2bf(b.w);
    return f;
}

// Block-role fused kernel (R14 config): blocks [0, histBlk) histogram dst>>BSH
// into bin-major hist2d[bin*nblk + blk] (plain stores, no global atomics);
// blocks [histBlk, ..) do z = x @ W^T + b via MFMA bf16, LDS-free.
// zxb[row*64+c] = { bf16(z_c) | bf16(x_c)<<16 }.
__global__ __launch_bounds__(256) void gemm_z_hist(const float* __restrict__ x,
                                                   const float* __restrict__ W,
                                                   const float* __restrict__ b,
                                                   unsigned int* __restrict__ zxb,
                                                   int n,
                                                   const int* __restrict__ dst,
                                                   int* __restrict__ hist2d,
                                                   int e_cnt, int histBlk,
                                                   int nb, int nblk) {
    __shared__ int cnt[2048];       // hist branch only (8 KB; nb <= 2048)
    int tid = threadIdx.x;

    if ((int)blockIdx.x < histBlk) {
        for (int i = tid; i < nb; i += 256) cnt[i] = 0;
        __syncthreads();
        int base = blockIdx.x * (256 * HEPT_H);
        for (int j = 0; j < HEPT_H; ++j) {
            int e = base + j * 256 + tid;
            if (e < e_cnt) atomicAdd(&cnt[dst[e] >> BSH], 1);   // LDS atomic
        }
        __syncthreads();
        for (int i = tid; i < nb; i += 256)
            hist2d[(size_t)i * nblk + blockIdx.x] = cnt[i];     // bin-major store
        return;
    }

    int row0 = (blockIdx.x - histBlk) * 64;
    int l  = tid & 63;    // lane
    int w  = tid >> 6;    // wave 0..3 -> rows w*16..w*16+15
    int lr = l & 15;      // A-row / B-col / D-col within 16-tile
    int hi = l >> 4;      // 0..3
    int lk = hi * 8;      // k offset within K=32 chunk

    // A frags straight from global: wave reads 16 contiguous 256B rows (4 KB)
    int arow = row0 + w * 16 + lr;
    int crow = (arow < n) ? arow : (n - 1);       // clamp; stores are guarded
    const float* xp = x + (size_t)crow * 64;
    frag_ab afr[2];
#pragma unroll
    for (int ks = 0; ks < 2; ++ks) {
        const float* ap = xp + ks * 32 + lk;
        afr[ks] = pack8(*(const float4*)ap, *(const float4*)(ap + 4));
    }

    // B frags straight from W (16 KB, L1/L2-resident; B^T == W so k contiguous)
    frag_ab bfr[4][2];
#pragma unroll
    for (int colt = 0; colt < 4; ++colt) {
#pragma unroll
        for (int ks = 0; ks < 2; ++ks) {
            const float* wp = W + (colt * 16 + lr) * 64 + ks * 32 + lk;
            bfr[colt][ks] = pack8(*(const float4*)wp, *(const float4*)(wp + 4));
        }
    }

    f32x4 zero = {0.f, 0.f, 0.f, 0.f};
    f32x4 acc[4] = {zero, zero, zero, zero};
#pragma unroll
    for (int ks = 0; ks < 2; ++ks) {
#pragma unroll
        for (int colt = 0; colt < 4; ++colt) {
            acc[colt] = __builtin_amdgcn_mfma_f32_16x16x32_bf16(
                afr[ks], bfr[colt][ks], acc[colt], 0, 0, 0);
        }
    }

    // D mapping: col=lane&15, row=(lane>>4)*4+reg (m89-verified).
    // xv re-read from global is L1-hot (this block just streamed these rows).
#pragma unroll
    for (int colt = 0; colt < 4; ++colt) {
        int col = colt * 16 + lr;
        float bb = b[col];
#pragma unroll
        for (int r = 0; r < 4; ++r) {
            int row = row0 + w * 16 + hi * 4 + r;
            int rrow = (row < n) ? row : (n - 1);
            float z  = acc[colt][r] + bb;
            float xv = x[(size_t)rrow * 64 + col];
            unsigned int u = (unsigned int)f2bf(z) |
                             ((unsigned int)f2bf(xv) << 16);
            if (row < n)
                zxb[(size_t)row * 64 + col] = u;   // 64B-segment coalesced
        }
    }
}

// ---- 3-phase coalesced scan over the bin-major histogram (atomic-free) ----
__global__ __launch_bounds__(256) void scan_part(const int* __restrict__ data,
                                                 int* __restrict__ part, int n) {
    __shared__ int red[256];
    int t = threadIdx.x;
    int i = blockIdx.x * 256 + t;
    red[t] = (i < n) ? data[i] : 0;
    __syncthreads();
    for (int off = 128; off >= 1; off >>= 1) {
        if (t < off) red[t] += red[t + off];
        __syncthreads();
    }
    if (t == 0) part[blockIdx.x] = red[0];
}

__global__ __launch_bounds__(1024) void scan_top(int* __restrict__ part, int B) {
    __shared__ int s[1024];
    int t = threadIdx.x;
    int v = (t < B) ? part[t] : 0;
    s[t] = v;
    __syncthreads();
    for (int off = 1; off < 1024; off <<= 1) {
        int u = (t >= off) ? s[t - off] : 0;
        __syncthreads();
        s[t] += u;
        __syncthreads();
    }
    if (t < B) part[t] = s[t] - v;   // exclusive
}

// in-place exclusive scan finalize (read-before-write, 1 thread per index).
// Writes total at data[n] as sentinel.
__global__ __launch_bounds__(256) void scan_final_ip(int* data,
                                                     const int* __restrict__ part, int n) {
    __shared__ int s[256];
    int t = threadIdx.x;
    int i = blockIdx.x * 256 + t;
    int v = (i < n) ? data[i] : 0;
    s[t] = v;
    __syncthreads();
    for (int off = 1; off < 256; off <<= 1) {
        int u = (t >= off) ? s[t - off] : 0;
        __syncthreads();
        s[t] += u;
        __syncthreads();
    }
    int incl = s[t] + part[blockIdx.x];
    if (i < n) data[i] = incl - v;
    if (i == n - 1) data[n] = incl;
}

// Partition edges into 128-node buckets: packed[pos] = src | (dst&127)<<24.
// Per-block bases come straight from the scanned 2D histogram -> disjoint output
// ranges with ZERO global atomics. SAME 8192-edge chunk (147 blocks, 10.5-int
// runs preserved — R8 lesson) at 1024 threads: 16 waves/CU, depth 8 (R14 win).
__global__ __launch_bounds__(1024) void msd_scatter(const int* __restrict__ src,
                                                    const int* __restrict__ dst,
                                                    const int* __restrict__ histS,
                                                    unsigned int* __restrict__ packed,
                                                    int e_cnt, int nb, int nblk) {
    __shared__ int cnt[1024];
    int t = threadIdx.x;
    int blk = blockIdx.x;
    for (int i = t; i < nb; i += 1024) cnt[i] = histS[(size_t)i * nblk + blk];
    __syncthreads();
    int base = blk * (1024 * SEPT);
    for (int j = 0; j < SEPT; ++j) {
        int e = base + j * 1024 + t;
        if (e < e_cnt) {
            int d = dst[e];
            int pos = atomicAdd(&cnt[d >> BSH], 1);          // LDS atomic only
            packed[pos] = (unsigned int)src[e] | ((unsigned int)(d & (BSZ - 1)) << 24);
        }
    }
}

// One block per 128-node bucket (~1536 edges avg, 782 blocks) at 1024 threads
// (R14 wave-depth treatment): 3 passes over the bucket go from ~6 serial
// dependent rounds each to ~1.5. Scan section stays 128-wide (guards t<128;
// all threads reach the barriers).
__global__ __launch_bounds__(1024) void bucket_csr(const unsigned int* __restrict__ packed,
                                                   const int* __restrict__ histS,
                                                   int* __restrict__ rowstart,
                                                   int* __restrict__ srcids,
                                                   int n, int e_cnt, int nb, int nblk) {
    __shared__ int cnt[128];
    __shared__ int sc[128];
    __shared__ int cur[128];
    int t = threadIdx.x;
    int b = blockIdx.x;
    int lo = histS[(size_t)b * nblk];
    int hi = histS[(size_t)(b + 1) * nblk];   // b==nb-1 hits sentinel == e_cnt
    int m = hi - lo;

    if (t < 128) cnt[t] = 0;
    __syncthreads();
    for (int i = t; i < m; i += 1024)
        atomicAdd(&cnt[packed[lo + i] >> 24], 1);
    __syncthreads();
    if (t < 128) sc[t] = cnt[t];
    __syncthreads();
    for (int off = 1; off < 128; off <<= 1) {
        int u = (t < 128 && t >= off) ? sc[t - off] : 0;
        __syncthreads();
        if (t < 128) sc[t] += u;
        __syncthreads();
    }
    if (t < 128) {
        int excl = sc[t] - cnt[t];
        cur[t] = lo + excl;
        int node = (b << BSH) + t;
        if (node < n) rowstart[node] = lo + excl;
    }
    if (b == nb - 1 && t == 0) rowstart[n] = e_cnt;
    __syncthreads();
    for (int i = t; i < m; i += 1024) {
        unsigned int p = packed[lo + i];
        int pos = atomicAdd(&cur[p >> 24], 1);     // LDS atomic
        srcids[pos] = (int)(p & 0xFFFFFFu);
    }
}

// wave-per-node, quarter-wave per edge, 8 edges/iter (2x unroll); unmasked full
// iterations + one masked tail. lrelu = max(v, 0.2v) (2 ops, slope < 1).
// bf16-packed row: zxb[row*64 + d] = { bf16 z_d | bf16 x_d << 16 }, 256 B/row.
__global__ __launch_bounds__(256) void gather4b(const int* __restrict__ srcids,
                                                const int* __restrict__ rowstart,
                                                const unsigned int* __restrict__ zxb,
                                                const float* __restrict__ att,
                                                float* __restrict__ out, int n) {
    int lane = threadIdx.x & 63;
    int node = blockIdx.x * 4 + (threadIdx.x >> 6);
    if (node >= n) return;
    int q = lane & 15;                 // dim group: 4q..4q+3
    int h = lane >> 4;                 // edge slot 0..3
    int rs = rowstart[node], re = rowstart[node + 1];

    const uint4 zdv = *(const uint4*)(zxb + (size_t)node * 64 + 4 * q);
    float zd0 = __uint_as_float(zdv.x << 16);
    float zd1 = __uint_as_float(zdv.y << 16);
    float zd2 = __uint_as_float(zdv.z << 16);
    float zd3 = __uint_as_float(zdv.w << 16);
    float4 av = *(const float4*)(att + 4 * q);
    float a0 = av.x * LOG2E, a1 = av.y * LOG2E, a2 = av.z * LOG2E, a3 = av.w * LOG2E;

    float ax0 = 0.f, ax1 = 0.f, ax2 = 0.f, ax3 = 0.f, ssum = 0.f;
    int efull = rs + ((re - rs) & ~7);
    int e = rs;
    for (; e < efull; e += 8) {            // unmasked body
        int s0 = srcids[e + h];
        int s1 = srcids[e + 4 + h];
        const uint4 r0 = *(const uint4*)(zxb + (size_t)s0 * 64 + 4 * q);
        const uint4 r1 = *(const uint4*)(zxb + (size_t)s1 * 64 + 4 * q);

        float v0 = __uint_as_float(r0.x << 16) + zd0; v0 = fmaxf(v0, 0.2f * v0);
        float v1 = __uint_as_float(r0.y << 16) + zd1; v1 = fmaxf(v1, 0.2f * v1);
        float v2 = __uint_as_float(r0.z << 16) + zd2; v2 = fmaxf(v2, 0.2f * v2);
        float v3 = __uint_as_float(r0.w << 16) + zd3; v3 = fmaxf(v3, 0.2f * v3);
        float p0 = v0 * a0 + v1 * a1 + v2 * a2 + v3 * a3;

        float u0 = __uint_as_float(r1.x << 16) + zd0; u0 = fmaxf(u0, 0.2f * u0);
        float u1 = __uint_as_float(r1.y << 16) + zd1; u1 = fmaxf(u1, 0.2f * u1);
        float u2 = __uint_as_float(r1.z << 16) + zd2; u2 = fmaxf(u2, 0.2f * u2);
        float u3 = __uint_as_float(r1.w << 16) + zd3; u3 = fmaxf(u3, 0.2f * u3);
        float p1 = u0 * a0 + u1 * a1 + u2 * a2 + u3 * a3;

#pragma unroll
        for (int off = 8; off >= 1; off >>= 1) {
            p0 += __shfl_xor(p0, off, 64);
            p1 += __shfl_xor(p1, off, 64);
        }
        float ex0 = __builtin_exp2f(p0);
        float ex1 = __builtin_exp2f(p1);
        ssum += ex0 + ex1;
        ax0 += ex0 * __uint_as_float(r0.x & 0xffff0000u)
             + ex1 * __uint_as_float(r1.x & 0xffff0000u);
        ax1 += ex0 * __uint_as_float(r0.y & 0xffff0000u)
             + ex1 * __uint_as_float(r1.y & 0xffff0000u);
        ax2 += ex0 * __uint_as_float(r0.z & 0xffff0000u)
             + ex1 * __uint_as_float(r1.z & 0xffff0000u);
        ax3 += ex0 * __uint_as_float(r0.w & 0xffff0000u)
             + ex1 * __uint_as_float(r1.w & 0xffff0000u);
    }
    if (e < re) {                          // masked tail (1..7 edges)
        int e0i = e + h, e1i = e + 4 + h;
        bool l0 = e0i < re, l1 = e1i < re;
        int s0 = l0 ? srcids[e0i] : node;
        int s1 = l1 ? srcids[e1i] : node;
        const uint4 r0 = *(const uint4*)(zxb + (size_t)s0 * 64 + 4 * q);
        const uint4 r1 = *(const uint4*)(zxb + (size_t)s1 * 64 + 4 * q);

        float v0 = __uint_as_float(r0.x << 16) + zd0; v0 = fmaxf(v0, 0.2f * v0);
        float v1 = __uint_as_float(r0.y << 16) + zd1; v1 = fmaxf(v1, 0.2f * v1);
        float v2 = __uint_as_float(r0.z << 16) + zd2; v2 = fmaxf(v2, 0.2f * v2);
        float v3 = __uint_as_float(r0.w << 16) + zd3; v3 = fmaxf(v3, 0.2f * v3);
        float p0 = v0 * a0 + v1 * a1 + v2 * a2 + v3 * a3;

        float u0 = __uint_as_float(r1.x << 16) + zd0; u0 = fmaxf(u0, 0.2f * u0);
        float u1 = __uint_as_float(r1.y << 16) + zd1; u1 = fmaxf(u1, 0.2f * u1);
        float u2 = __uint_as_float(r1.z << 16) + zd2; u2 = fmaxf(u2, 0.2f * u2);
        float u3 = __uint_as_float(r1.w << 16) + zd3; u3 = fmaxf(u3, 0.2f * u3);
        float p1 = u0 * a0 + u1 * a1 + u2 * a2 + u3 * a3;

#pragma unroll
        for (int off = 8; off >= 1; off >>= 1) {
            p0 += __shfl_xor(p0, off, 64);
            p1 += __shfl_xor(p1, off, 64);
        }
        float ex0 = l0 ? __builtin_exp2f(p0) : 0.f;
        float ex1 = l1 ? __builtin_exp2f(p1) : 0.f;
        ssum += ex0 + ex1;
        ax0 += ex0 * __uint_as_float(r0.x & 0xffff0000u)
             + ex1 * __uint_as_float(r1.x & 0xffff0000u);
        ax1 += ex0 * __uint_as_float(r0.y & 0xffff0000u)
             + ex1 * __uint_as_float(r1.y & 0xffff0000u);
        ax2 += ex0 * __uint_as_float(r0.z & 0xffff0000u)
             + ex1 * __uint_as_float(r1.z & 0xffff0000u);
        ax3 += ex0 * __uint_as_float(r0.w & 0xffff0000u)
             + ex1 * __uint_as_float(r1.w & 0xffff0000u);
    }
    ssum += __shfl_xor(ssum, 16, 64); ssum += __shfl_xor(ssum, 32, 64);
    ax0  += __shfl_xor(ax0, 16, 64);  ax0  += __shfl_xor(ax0, 32, 64);
    ax1  += __shfl_xor(ax1, 16, 64);  ax1  += __shfl_xor(ax1, 32, 64);
    ax2  += __shfl_xor(ax2, 16, 64);  ax2  += __shfl_xor(ax2, 32, 64);
    ax3  += __shfl_xor(ax3, 16, 64);  ax3  += __shfl_xor(ax3, 32, 64);
    if (h == 0) {
        float inv = (re > rs) ? 1.f / ssum : 0.f;
        float4 o = make_float4(ax0 * inv, ax1 * inv, ax2 * inv, ax3 * inv);
        *(float4*)&out[(size_t)node * D + 4 * q] = o;
    }
}

extern "C" void kernel_launch(void* const* d_in, const int* in_sizes, int n_in,
                              void* d_out, int out_size, void* d_ws, size_t ws_size,
                              hipStream_t stream) {
    const float* x   = (const float*)d_in[0];
    const int*   ei  = (const int*)d_in[1];
    const float* W   = (const float*)d_in[2];
    const float* b   = (const float*)d_in[3];
    const float* att = (const float*)d_in[4];
    int n = in_sizes[0] / D;
    int e = in_sizes[1] / 2;
    const int* src = ei;
    const int* dst = ei + e;
    float* out = (float*)d_out;

    int gemmBlk = (n + 63) / 64;                             // 1563
    int nb      = (n + BSZ - 1) >> BSH;                      // 782 buckets of 128
    int histBlk = (e + 256 * HEPT_H - 1) / (256 * HEPT_H);   // 147
    int nblk    = histBlk;
    int scatBlk = (e + 1024 * SEPT - 1) / (1024 * SEPT);     // 147 (same chunks)
    int NBH     = nb * nblk;                                 // 114954 cells
    int scanBlk = (NBH + 255) / 256;                         // 450 (<= 1024)

    // ws: zxb[n*64 uint] | hist2d[NBH+1] | rowstart[n+1] | srcids[e] | packed[e] | part[1024]
    unsigned int* zxb = (unsigned int*)d_ws;
    int* hist2d   = (int*)(zxb + (size_t)n * 64);
    int* rowstart = hist2d + NBH + 1;
    int* srcids   = rowstart + n + 1;
    unsigned int* packed = (unsigned int*)(srcids + e);
    int* part     = (int*)(packed + e);

    gemm_z_hist<<<histBlk + gemmBlk, 256, 0, stream>>>(x, W, b, zxb, n,
                                                       dst, hist2d, e, histBlk, nb, nblk);
    scan_part<<<scanBlk, 256, 0, stream>>>(hist2d, part, NBH);
    scan_top<<<1, 1024, 0, stream>>>(part, scanBlk);
    scan_final_ip<<<scanBlk, 256, 0, stream>>>(hist2d, part, NBH);
    msd_scatter<<<scatBlk, 1024, 0, stream>>>(src, dst, hist2d, packed, e, nb, nblk);
    bucket_csr<<<nb, 1024, 0, stream>>>(packed, hist2d, rowstart, srcids, n, e, nb, nblk);
    gather4b<<<(n + 3) / 4, 256, 0, stream>>>(srcids, rowstart, zxb, att, out, n);
}